// Round 4
// baseline (239.626 us; speedup 1.0000x reference)
//
#include <hip/hip_runtime.h>
#include <stdint.h>

// MFMA fragment types (gfx950)
typedef __attribute__((ext_vector_type(8))) short short8;  // 8 bf16 = 4 VGPRs
typedef __attribute__((ext_vector_type(4))) float f32x4;   // 4 fp32 acc

static_assert(sizeof(short8) == 16, "frag size");

__device__ __forceinline__ uint16_t f2bf(float f) {
  uint32_t u = __builtin_bit_cast(uint32_t, f);
  u += 0x7fffu + ((u >> 16) & 1u);
  return (uint16_t)(u >> 16);
}

__device__ __forceinline__ void gload_lds16(const void* g, void* lds_wave_base) {
  // async global->LDS, 16B/lane; LDS dst = wave-uniform base + lane*16
  __builtin_amdgcn_global_load_lds(
      (__attribute__((address_space(1))) void*)(void*)(g),
      (__attribute__((address_space(3))) void*)(lds_wave_base),
      16, 0, 0);
}

// Swizzle convention (all bf16 staging): within each 64-elem K-group, 16B
// chunk c of row r is stored at chunk c ^ (r&7). DMA stages tiles verbatim;
// fragment reads at chunk (h*4+q)^(r&7) are conflict-free ds_read_b128.

// ---------------------------------------------------------------------------
// quant: dwT[o][i] = ternary(weight[i][o]) in {-1,0,+1} bf16, swizzled.
// ---------------------------------------------------------------------------
__global__ __launch_bounds__(256) void quant_kernel(const float* __restrict__ w,
                                                    uint16_t* __restrict__ dwT) {
  const int o = blockIdx.x, i = threadIdx.x;
  const float v = w[i * 256 + o];
  const float t = (v > 0.01f) ? 1.0f : ((v < -0.01f) ? -1.0f : 0.0f);
  dwT[o * 256 + (i ^ ((o & 7) << 3))] = f2bf(t);
}

// ---------------------------------------------------------------------------
// support: spt[o][g] = bf16(0.01 * sum_i x[g][i] * tern[i][o]), swizzled cols.
// Tile [128 g][64 o], K=256 (BK=64). 512 blocks x 256 thr. (verified R2/R3)
// ---------------------------------------------------------------------------
#define SB_A 0       // [128][64] bf16 swizzled, 16384 B (reused in epilogue)
#define SB_B 16384   // [64][64] bf16, 8192 B

__global__ __launch_bounds__(256) void support_kernel(const float* __restrict__ x,
                                                      const uint16_t* __restrict__ dwT,
                                                      uint16_t* __restrict__ spt) {
  __shared__ __align__(16) unsigned char smem[24576];
  const int t = threadIdx.x, lane = t & 63, w = t >> 6;
  const int r = lane & 15, q = lane >> 4;
  const int g0 = (blockIdx.x & 127) * 128;
  const int o0 = (blockIdx.x >> 7) * 64;

  f32x4 acc[2][4] = {};

  for (int k0 = 0; k0 < 256; k0 += 64) {
#pragma unroll
    for (int it = 0; it < 4; ++it) {
      const int id = it * 256 + t, row = id >> 3, c = id & 7;
      const float* p = x + (size_t)(g0 + row) * 256 + k0 + c * 8;
      const float4 v0 = *(const float4*)p;
      const float4 v1 = *(const float4*)(p + 4);
      uint4 u;
      u.x = (uint32_t)f2bf(v0.x) | ((uint32_t)f2bf(v0.y) << 16);
      u.y = (uint32_t)f2bf(v0.z) | ((uint32_t)f2bf(v0.w) << 16);
      u.z = (uint32_t)f2bf(v1.x) | ((uint32_t)f2bf(v1.y) << 16);
      u.w = (uint32_t)f2bf(v1.z) | ((uint32_t)f2bf(v1.w) << 16);
      *(uint4*)(smem + SB_A + row * 128 + ((c ^ (row & 7)) << 4)) = u;
    }
#pragma unroll
    for (int j = 0; j < 2; ++j) {
      const int id = j * 256 + t, row = id >> 3, c = id & 7;
      gload_lds16(dwT + (size_t)(o0 + row) * 256 + k0 + c * 8,
                  smem + SB_B + (size_t)(j * 256 + w * 64) * 16);
    }
    __syncthreads();
#pragma unroll
    for (int h = 0; h < 2; ++h) {
      short8 av[2], bv[4];
      const int pc = (((h * 4 + q) ^ (r & 7)) << 4);
#pragma unroll
      for (int mi = 0; mi < 2; ++mi)
        av[mi] = *(const short8*)(smem + SB_A + (32 * w + 16 * mi + r) * 128 + pc);
#pragma unroll
      for (int ni = 0; ni < 4; ++ni)
        bv[ni] = *(const short8*)(smem + SB_B + (16 * ni + r) * 128 + pc);
#pragma unroll
      for (int mi = 0; mi < 2; ++mi)
#pragma unroll
        for (int ni = 0; ni < 4; ++ni)
          acc[mi][ni] = __builtin_amdgcn_mfma_f32_16x16x32_bf16(av[mi], bv[ni],
                                                                acc[mi][ni], 0, 0, 0);
    }
    __syncthreads();
  }
  // epilogue: LDS transpose -> coalesced dwordx4 stores of spt rows
#pragma unroll
  for (int ni = 0; ni < 4; ++ni) {
    const int ol = 16 * ni + r;
#pragma unroll
    for (int mi = 0; mi < 2; ++mi)
#pragma unroll
      for (int reg = 0; reg < 4; ++reg) {
        const int gl = 32 * w + 16 * mi + 4 * q + reg;      // C row = g
        const int gsw = gl ^ ((ol & 7) << 3);               // global col swizzle
        *(uint16_t*)(smem + (ol * 128 + gsw) * 2) = f2bf(acc[mi][ni][reg] * 0.01f);
      }
  }
  __syncthreads();
#pragma unroll
  for (int it = 0; it < 4; ++it) {
    const int id = it * 256 + t, row = id >> 4, cc = id & 15;
    const uint4 u = *(const uint4*)(smem + (row * 128 + cc * 8) * 2);
    *(uint4*)(spt + (size_t)(o0 + row) * 16384 + g0 + cc * 8) = u;
  }
}

// ---------------------------------------------------------------------------
// main (fused convert, DOUBLE-BUFFERED): out = relu(adj @ support + bias)
// Tile [32 n][256 o], K=2048 (BK=64). Grid 512 = 8 bb x 64 n-tiles; adj fp32
// read exactly once. Per-iter pipeline: barrier -> issue B-DMA(k+1) + A
// global loads(k+1) -> compute(k) -> convert+ds_write A(k+1). One barrier
// per K-step; DMA/HBM latency hidden behind the compute phase.
// ---------------------------------------------------------------------------
#define MBUF 36864   // per-stage: A [32][64] @0 (4096 B) + B [256][64] @4096 (32768 B)

__global__ __launch_bounds__(256) void gcn_main_kernel(const float* __restrict__ adj,
                                                       const uint16_t* __restrict__ spt,
                                                       const float* __restrict__ bias,
                                                       float* __restrict__ out) {
  __shared__ __align__(16) unsigned char smem[2 * MBUF];
  const int t = threadIdx.x, lane = t & 63, w = t >> 6;
  const int r = lane & 15, q = lane >> 4;
  const int bb = blockIdx.x & 7;             // batch -> XCD affinity (spt[bb] L2-resident)
  const int n0 = (blockIdx.x >> 3) * 32;     // n-tile
  const float* adjb = adj + ((size_t)bb * 2048 + n0) * 2048;
  const uint16_t* sptb = spt + (size_t)bb * 2048;

  const int arow = t >> 3, ac = t & 7;       // A-staging: 32 rows x 8 chunks
  const float* aptr = adjb + (size_t)arow * 2048 + ac * 8;
  const int aoff = arow * 128 + ((ac ^ (arow & 7)) << 4);  // swizzled LDS byte off

  f32x4 acc[2][4] = {};

  // ---- prologue: stage k-step 0 into buffer 0
  {
#pragma unroll
    for (int j = 0; j < 8; ++j) {
      const int id = j * 256 + t, row = id >> 3, c = id & 7;
      gload_lds16(sptb + (size_t)row * 16384 + c * 8,
                  smem + 4096 + (size_t)(j * 256 + w * 64) * 16);
    }
    const float4 v0 = *(const float4*)(aptr);
    const float4 v1 = *(const float4*)(aptr + 4);
    uint4 u;
    u.x = (uint32_t)f2bf(v0.x) | ((uint32_t)f2bf(v0.y) << 16);
    u.y = (uint32_t)f2bf(v0.z) | ((uint32_t)f2bf(v0.w) << 16);
    u.z = (uint32_t)f2bf(v1.x) | ((uint32_t)f2bf(v1.y) << 16);
    u.w = (uint32_t)f2bf(v1.z) | ((uint32_t)f2bf(v1.w) << 16);
    *(uint4*)(smem + aoff) = u;
  }

  for (int k = 0; k < 32; ++k) {
    const int p = k & 1;
    unsigned char* cur = smem + p * MBUF;
    unsigned char* nxt = smem + (p ^ 1) * MBUF;
    __syncthreads();   // buf[p] ready (prev iter's DMA drained + A written)

    float4 v0, v1;
    const bool pf = (k + 1) < 32;
    if (pf) {
      const int k1 = (k + 1) * 64;
      // B: spt tile for k+1, verbatim DMA into nxt
#pragma unroll
      for (int j = 0; j < 8; ++j) {
        const int id = j * 256 + t, row = id >> 3, c = id & 7;
        gload_lds16(sptb + (size_t)row * 16384 + k1 + c * 8,
                    nxt + 4096 + (size_t)(j * 256 + w * 64) * 16);
      }
      // A: issue global loads for k+1 (land during compute)
      v0 = *(const float4*)(aptr + k1);
      v1 = *(const float4*)(aptr + k1 + 4);
    }

    // ---- compute step k from cur
#pragma unroll
    for (int h = 0; h < 2; ++h) {
      short8 av[2], bv[4];
      const int pc = (((h * 4 + q) ^ (r & 7)) << 4);
#pragma unroll
      for (int mi = 0; mi < 2; ++mi)
        av[mi] = *(const short8*)(cur + (16 * mi + r) * 128 + pc);
#pragma unroll
      for (int ni = 0; ni < 4; ++ni)
        bv[ni] = *(const short8*)(cur + 4096 + (w * 64 + 16 * ni + r) * 128 + pc);
#pragma unroll
      for (int mi = 0; mi < 2; ++mi)
#pragma unroll
        for (int ni = 0; ni < 4; ++ni)
          acc[mi][ni] = __builtin_amdgcn_mfma_f32_16x16x32_bf16(av[mi], bv[ni],
                                                                acc[mi][ni], 0, 0, 0);
    }

    if (pf) {
      // A: convert + swizzled b128 write into nxt
      uint4 u;
      u.x = (uint32_t)f2bf(v0.x) | ((uint32_t)f2bf(v0.y) << 16);
      u.y = (uint32_t)f2bf(v0.z) | ((uint32_t)f2bf(v0.w) << 16);
      u.z = (uint32_t)f2bf(v1.x) | ((uint32_t)f2bf(v1.y) << 16);
      u.w = (uint32_t)f2bf(v1.z) | ((uint32_t)f2bf(v1.w) << 16);
      *(uint4*)(nxt + aoff) = u;
    }
  }

  // ---- epilogue: +bias, relu, fp32 store
#pragma unroll
  for (int ni = 0; ni < 4; ++ni) {
    const int o = w * 64 + 16 * ni + r;      // C col = N = o
    const float bs = bias[o];
#pragma unroll
    for (int mi = 0; mi < 2; ++mi)
#pragma unroll
      for (int reg = 0; reg < 4; ++reg) {
        const int n = n0 + 16 * mi + 4 * q + reg;  // C row = M = n
        out[((size_t)bb * 2048 + n) * 256 + o] = fmaxf(acc[mi][ni][reg] + bs, 0.0f);
      }
  }
}

// ---------------------------------------------------------------------------
extern "C" void kernel_launch(void* const* d_in, const int* in_sizes, int n_in,
                              void* d_out, int out_size, void* d_ws, size_t ws_size,
                              hipStream_t stream) {
  const float* x      = (const float*)d_in[0];  // [8,2048,256]
  const float* adj    = (const float*)d_in[1];  // [8,2048,2048]
  const float* weight = (const float*)d_in[2];  // [256,256]
  const float* bias   = (const float*)d_in[3];  // [256]
  float* out = (float*)d_out;                   // [8,2048,256]

  uint16_t* dwT = (uint16_t*)d_ws;                          // 128 KB
  uint16_t* spt = (uint16_t*)((char*)d_ws + 131072);        // 8 MB

  hipLaunchKernelGGL(quant_kernel,    dim3(256), dim3(256), 0, stream, weight, dwT);
  hipLaunchKernelGGL(support_kernel,  dim3(512), dim3(256), 0, stream, x, dwT, spt);
  hipLaunchKernelGGL(gcn_main_kernel, dim3(512), dim3(256), 0, stream, adj, spt, bias, out);
}